// Round 3
// baseline (483.098 us; speedup 1.0000x reference)
//
#include <hip/hip_runtime.h>
#include <hip/hip_bf16.h>

// Sizes (fixed by problem)
#define BATCH 8
#define CDIM  512
#define NPOS  4096
#define KDQK  64
#define ODIM  512

typedef __attribute__((ext_vector_type(8)))  short short8v;   // 8 bf16 (MFMA A/B frag)
typedef __attribute__((ext_vector_type(16))) float f32x16;    // MFMA 32x32 C/D frag

static __device__ __forceinline__ unsigned short f2bf(float f) {
    union { __hip_bfloat16 h; unsigned short u; } cv;
    cv.h = __float2bfloat16(f);
    return cv.u;
}
static __device__ __forceinline__ float bf2f(unsigned short u) {
    union { unsigned short u; __hip_bfloat16 h; } cv;
    cv.u = u;
    return __bfloat162float(cv.h);
}

// async global->LDS 16B (wave-uniform LDS base + lane*16, per-lane global src)
static __device__ __forceinline__ void gload_lds16(const unsigned short* g, unsigned short* s) {
    __builtin_amdgcn_global_load_lds((const __attribute__((address_space(1))) unsigned int*)g,
                                     (__attribute__((address_space(3))) unsigned int*)s, 16, 0, 0);
}

static __device__ __forceinline__ int cvtpk(float a, float b) {
    int r;
    asm("v_cvt_pk_bf16_f32 %0, %1, %2" : "=v"(r) : "v"(a), "v"(b));
    return r;
}

#if __has_builtin(__builtin_amdgcn_exp2f)
static __device__ __forceinline__ float exp2_raw(float x) { return __builtin_amdgcn_exp2f(x); }
#else
static __device__ __forceinline__ float exp2_raw(float x) { return exp2f(x); }
#endif

// ---------------------------------------------------------------------------
// Kernel 1: convert q_w/k_w/v_w fp32 -> bf16 into workspace
// ---------------------------------------------------------------------------
__global__ __launch_bounds__(256) void wconv_kernel(const float* __restrict__ qw,
                                                    const float* __restrict__ kw,
                                                    const float* __restrict__ vw,
                                                    unsigned short* __restrict__ wq,
                                                    unsigned short* __restrict__ wk,
                                                    unsigned short* __restrict__ wv) {
    int idx = blockIdx.x * 256 + threadIdx.x;
    if (idx < 32768)        wq[idx]          = f2bf(qw[idx]);
    else if (idx < 65536)   wk[idx - 32768]  = f2bf(kw[idx - 32768]);
    else if (idx < 327680)  wv[idx - 65536]  = f2bf(vw[idx - 65536]);
}

// ---------------------------------------------------------------------------
// Kernel 2: x [B][C][N] fp32 -> xT [B][N][C] bf16   (64x64 tiles via LDS)
// ---------------------------------------------------------------------------
__global__ __launch_bounds__(256) void xpose_kernel(const float* __restrict__ x,
                                                    unsigned short* __restrict__ xT) {
    __shared__ float xs[64][65];
    const int b = blockIdx.z, c0 = blockIdx.y * 64, n0 = blockIdx.x * 64;
    const int t = threadIdx.x;
    #pragma unroll
    for (int it = 0; it < 4; ++it) {
        int lin = it * 256 + t;
        int c = lin >> 4, nq = lin & 15;
        const float4 v = *reinterpret_cast<const float4*>(
            x + ((size_t)(b * CDIM + c0 + c) * NPOS + n0 + nq * 4));
        xs[c][nq * 4 + 0] = v.x; xs[c][nq * 4 + 1] = v.y;
        xs[c][nq * 4 + 2] = v.z; xs[c][nq * 4 + 3] = v.w;
    }
    __syncthreads();
    #pragma unroll
    for (int it = 0; it < 4; ++it) {
        int lin = it * 256 + t;
        int n = lin >> 4, cq = lin & 15;
        ushort4 u;
        u.x = f2bf(xs[cq * 4 + 0][n]); u.y = f2bf(xs[cq * 4 + 1][n]);
        u.z = f2bf(xs[cq * 4 + 2][n]); u.w = f2bf(xs[cq * 4 + 3][n]);
        *reinterpret_cast<ushort4*>(xT + ((size_t)(b * NPOS + n0 + n) * CDIM + c0 + cq * 4)) = u;
    }
}

// ---------------------------------------------------------------------------
// Kernel 3: projection GEMM  Y = (W * x + bias) * scale
//   TRANS=1: Y[b][n][r]  (position-major, for Q/K, R=64)
//   TRANS=0: Y[b][r][n]  (natural, for V, R=512)
// ---------------------------------------------------------------------------
template <int TRANS>
__global__ __launch_bounds__(256) void proj_kernel(const unsigned short* __restrict__ W,
                                                   const float* __restrict__ bias,
                                                   const unsigned short* __restrict__ xT,
                                                   unsigned short* __restrict__ Y,
                                                   float scale) {
    __shared__ unsigned short Wl[64][64];
    __shared__ unsigned short Xl[64][64];
    const int b = blockIdx.z, r0 = blockIdx.y * 64, n0 = blockIdx.x * 64;
    const int t = threadIdx.x, wave = t >> 6, lane = t & 63, hi = lane >> 5, lo = lane & 31;
    const int wr = wave >> 1, wc = wave & 1;

    f32x16 acc;
    #pragma unroll
    for (int q = 0; q < 16; ++q) acc[q] = 0.f;

    for (int ck = 0; ck < CDIM; ck += 64) {
        __syncthreads();
        #pragma unroll
        for (int it = 0; it < 2; ++it) {
            int lin = it * 256 + t;
            int r = lin >> 3, c8 = lin & 7;
            int4 v = *reinterpret_cast<const int4*>(W + ((size_t)(r0 + r) * CDIM + ck + c8 * 8));
            *reinterpret_cast<int4*>(&Wl[r][(c8 ^ (r & 7)) * 8]) = v;
        }
        #pragma unroll
        for (int it = 0; it < 2; ++it) {
            int lin = it * 256 + t;
            int n = lin >> 3, c8 = lin & 7;
            int4 v = *reinterpret_cast<const int4*>(
                xT + ((size_t)(b * NPOS + n0 + n) * CDIM + ck + c8 * 8));
            *reinterpret_cast<int4*>(&Xl[n][(c8 ^ (n & 7)) * 8]) = v;
        }
        __syncthreads();
        const int ar = wr * 32 + lo, bn = wc * 32 + lo;
        #pragma unroll
        for (int ks = 0; ks < 4; ++ks) {
            int chunk = 2 * ks + hi;
            short8v a  = *reinterpret_cast<const short8v*>(&Wl[ar][(chunk ^ (ar & 7)) * 8]);
            short8v bb = *reinterpret_cast<const short8v*>(&Xl[bn][(chunk ^ (bn & 7)) * 8]);
            acc = __builtin_amdgcn_mfma_f32_32x32x16_bf16(a, bb, acc, 0, 0, 0);
        }
    }

    const int n = n0 + wc * 32 + lo;
    if (TRANS) {
        #pragma unroll
        for (int g = 0; g < 4; ++g) {
            int rbase = wr * 32 + g * 8 + hi * 4;
            ushort4 u;
            u.x = f2bf((acc[4 * g + 0] + bias[r0 + rbase + 0]) * scale);
            u.y = f2bf((acc[4 * g + 1] + bias[r0 + rbase + 1]) * scale);
            u.z = f2bf((acc[4 * g + 2] + bias[r0 + rbase + 2]) * scale);
            u.w = f2bf((acc[4 * g + 3] + bias[r0 + rbase + 3]) * scale);
            *reinterpret_cast<ushort4*>(Y + ((size_t)(b * NPOS + n) * KDQK + r0 + rbase)) = u;
        }
    } else {
        #pragma unroll
        for (int q = 0; q < 16; ++q) {
            int r = r0 + wr * 32 + (q & 3) + 8 * (q >> 2) + 4 * hi;
            Y[(size_t)(b * ODIM + r) * NPOS + n] = f2bf((acc[q] + bias[r]) * scale);
        }
    }
}

// ---------------------------------------------------------------------------
// Kernel 4: flash attention + gamma*out + v   (R=1 softmax, full od per block)
//
// Block: 512 thr / 8 waves; covers QB=64 queries x od=512; j-tile JB=128.
// Wave w: S-tile (jh = w>>1, ih = w&1)  [8 tiles = 8 waves, no duplication];
// PV: wave w owns od slice [64w, 64w+64), V A-frags straight from L2
// (V[b] = 4MB pinned to XCD b via bid&7). P (64i x 128j bf16) through
// swizzled LDS; per-tile max/sum exchanged via tiny LDS buffers.
// Softmax state (m, l, c) per-lane (acc col = query = lane), computed
// redundantly-but-identically by all waves from the same LDS data.
// 2 barriers per tile. K double-buffered via global_load_lds (prefetch
// issued in phase B, drained by B2's implicit vmcnt(0)).
// ---------------------------------------------------------------------------
__global__ __launch_bounds__(512, 2) void attn_kernel(const unsigned short* __restrict__ Qt,
                                                      const unsigned short* __restrict__ Kt,
                                                      const unsigned short* __restrict__ V,
                                                      const float* __restrict__ gamma_p,
                                                      float* __restrict__ out) {
    __shared__ __align__(16) unsigned short Kbuf[2][128 * 64];  // rows 128B, pos = c ^ (row&7)
    __shared__ __align__(16) unsigned short Pl[64 * 128];       // rows 256B, pos = c ^ (row&15)
    __shared__ __align__(16) float maxb[64][4];                 // [i][jh]
    __shared__ __align__(16) float sumb[64][4];

    const int bid = blockIdx.x;
    const int b = bid & 7, qt = bid >> 3;
    const int i0 = qt * 64;
    const int tid = threadIdx.x, wid = tid >> 6, l = tid & 63, lo = l & 31, hi = l >> 5;
    const int jh = wid >> 1, ih = wid & 1;
    const int ow0 = wid * 64;

    // ---- K staging: 2 x 16B per thread per tile (pre-swizzled source)
    const int sidx0 = tid, sidx1 = 512 + tid;
    const int srow0 = sidx0 >> 3, srow1 = sidx1 >> 3;
    const unsigned short* kp0 = Kt + ((size_t)b * NPOS + srow0) * 64 + (((sidx0 & 7) ^ (srow0 & 7)) << 3);
    const unsigned short* kp1 = Kt + ((size_t)b * NPOS + srow1) * 64 + (((sidx1 & 7) ^ (srow1 & 7)) << 3);
    const int kd0 = sidx0 * 8, kd1 = sidx1 * 8;   // ushort offsets in Kbuf[bi]

    // ---- Q fragments (B-operand: lane = query col, 8 kd per chunk)
    short8v qf[4];
    {
        const unsigned short* qb = Qt + ((size_t)b * NPOS + i0 + ih * 32 + lo) * 64 + hi * 8;
        #pragma unroll
        for (int kc = 0; kc < 4; ++kc)
            qf[kc] = *reinterpret_cast<const short8v*>(qb + kc * 16);
    }

    f32x16 acc[2][2];
    #pragma unroll
    for (int odt = 0; odt < 2; ++odt)
        #pragma unroll
        for (int q = 0; q < 16; ++q) { acc[odt][0][q] = 0.f; acc[odt][1][q] = 0.f; }

    float mr0 = -1e30f, mr1 = -1e30f, lr0 = 0.f, lr1 = 0.f;

    // prologue: stage K tile 0
    gload_lds16(kp0, &Kbuf[0][kd0]);
    gload_lds16(kp1, &Kbuf[0][kd1]);
    __syncthreads();

    const int krow = jh * 32 + lo;
    const unsigned short* Vbase = V + ((size_t)b * ODIM + ow0 + lo) * NPOS + hi * 8;

    for (int t = 0; t < 32; ++t) {
        const int j0 = t * 128;
        const int bi = t & 1;

        // ---------------- Phase A: QK^T for this wave's S-tile ----------------
        f32x16 s;
        #pragma unroll
        for (int q = 0; q < 16; ++q) s[q] = 0.f;
        const unsigned short* KB = &Kbuf[bi][0];
        #pragma unroll
        for (int kc = 0; kc < 4; ++kc) {
            short8v a = *reinterpret_cast<const short8v*>(
                KB + krow * 64 + (((kc * 2 + hi) ^ (krow & 7)) << 3));
            s = __builtin_amdgcn_mfma_f32_32x32x16_bf16(a, qf[kc], s, 0, 0, 0);
        }
        // tile-max over 32 j for col i (lanes lo / lo+32 pair via shfl)
        float m01 = fmaxf(s[0], s[1]),   m23 = fmaxf(s[2], s[3]);
        float m45 = fmaxf(s[4], s[5]),   m67 = fmaxf(s[6], s[7]);
        float m89 = fmaxf(s[8], s[9]),   mab = fmaxf(s[10], s[11]);
        float mcd = fmaxf(s[12], s[13]), mef = fmaxf(s[14], s[15]);
        float mx = fmaxf(fmaxf(fmaxf(m01, m23), fmaxf(m45, m67)),
                         fmaxf(fmaxf(m89, mab), fmaxf(mcd, mef)));
        mx = fmaxf(mx, __shfl_xor(mx, 32));
        if (hi == 0) maxb[ih * 32 + lo][jh] = mx;
        __syncthreads();   // B1

        // ---------------- Phase B: softmax + P write ----------------
        if (t + 1 < 32) {  // prefetch next K tile (drains at B2)
            gload_lds16(kp0 + (size_t)(j0 + 128) * 64, &Kbuf[bi ^ 1][kd0]);
            gload_lds16(kp1 + (size_t)(j0 + 128) * 64, &Kbuf[bi ^ 1][kd1]);
        }
        float4 mv0 = *reinterpret_cast<const float4*>(&maxb[lo][0]);
        float4 mv1 = *reinterpret_cast<const float4*>(&maxb[32 + lo][0]);
        float mt0 = fmaxf(fmaxf(mv0.x, mv0.y), fmaxf(mv0.z, mv0.w));
        float mt1 = fmaxf(fmaxf(mv1.x, mv1.y), fmaxf(mv1.z, mv1.w));
        bool g0 = mt0 > mr0 + 12.f, g1 = mt1 > mr1 + 12.f;      // defer-max
        float c0 = g0 ? exp2_raw(mr0 - mt0) : 1.f;
        float c1 = g1 ? exp2_raw(mr1 - mt1) : 1.f;
        if (g0) mr0 = mt0;
        if (g1) mr1 = mt1;
        float msel = ih ? mr1 : mr0;

        float p[16];
        #pragma unroll
        for (int q = 0; q < 16; ++q) p[q] = exp2_raw(s[q] - msel);
        float t01 = (p[0] + p[1]) + (p[2] + p[3]);
        float t23 = (p[4] + p[5]) + (p[6] + p[7]);
        float t45 = (p[8] + p[9]) + (p[10] + p[11]);
        float t67 = (p[12] + p[13]) + (p[14] + p[15]);
        float ts = (t01 + t23) + (t45 + t67);
        ts += __shfl_xor(ts, 32);
        if (hi == 0) sumb[ih * 32 + lo][jh] = ts;

        {   // P write: rows j = jh*32 + 8m + 4hi + {0..3}, row i, swizzled chunks
            const int irow = ih * 32 + lo;
            const int rk = irow & 15;
            #pragma unroll
            for (int m = 0; m < 4; ++m) {
                int w0 = cvtpk(p[4 * m + 0], p[4 * m + 1]);
                int w1 = cvtpk(p[4 * m + 2], p[4 * m + 3]);
                int pos = (jh * 4 + m) ^ rk;
                *reinterpret_cast<int2*>(&Pl[irow * 128 + pos * 8 + hi * 4]) = make_int2(w0, w1);
            }
        }
        __syncthreads();   // B2 (also drains K prefetch)

        // ---------------- Phase C: PV + bookkeeping ----------------
        float4 sv0 = *reinterpret_cast<const float4*>(&sumb[lo][0]);
        float4 sv1 = *reinterpret_cast<const float4*>(&sumb[32 + lo][0]);
        float ts0 = (sv0.x + sv0.y) + (sv0.z + sv0.w);
        float ts1 = (sv1.x + sv1.y) + (sv1.z + sv1.w);
        lr0 = lr0 * c0 + ts0;
        lr1 = lr1 * c1 + ts1;
        if (__any(g0 || g1)) {
            #pragma unroll
            for (int odt = 0; odt < 2; ++odt)
                #pragma unroll
                for (int q = 0; q < 16; ++q) { acc[odt][0][q] *= c0; acc[odt][1][q] *= c1; }
        }
        const int rk = lo & 15;   // swizzle key for P rows lo and 32+lo (same)
        #pragma unroll
        for (int odt = 0; odt < 2; ++odt) {
            #pragma unroll
            for (int kc = 0; kc < 8; ++kc) {
                short8v av = *reinterpret_cast<const short8v*>(
                    Vbase + (size_t)odt * 32 * NPOS + j0 + kc * 16);
                int pos = ((kc * 2 + hi) ^ rk) * 8;
                short8v b0 = *reinterpret_cast<const short8v*>(&Pl[lo * 128 + pos]);
                short8v b1 = *reinterpret_cast<const short8v*>(&Pl[(32 + lo) * 128 + pos]);
                acc[odt][0] = __builtin_amdgcn_mfma_f32_32x32x16_bf16(av, b0, acc[odt][0], 0, 0, 0);
                acc[odt][1] = __builtin_amdgcn_mfma_f32_32x32x16_bf16(av, b1, acc[odt][1], 0, 0, 0);
            }
        }
    }

    // ---------------- epilogue: out = gamma*O/l + v ----------------
    float inv0 = 1.0f / lr0, inv1 = 1.0f / lr1;
    const float gm = gamma_p[0];
    #pragma unroll
    for (int odt = 0; odt < 2; ++odt) {
        #pragma unroll
        for (int it = 0; it < 2; ++it) {
            float inv = it ? inv1 : inv0;
            #pragma unroll
            for (int q = 0; q < 16; ++q) {
                int od = ow0 + odt * 32 + (q & 3) + 8 * (q >> 2) + 4 * hi;
                int i = i0 + it * 32 + lo;
                size_t addr = ((size_t)b * ODIM + od) * NPOS + i;
                out[addr] = gm * acc[odt][it][q] * inv + bf2f(V[addr]);
            }
        }
    }
}

// ---------------------------------------------------------------------------
// Host launcher
// ---------------------------------------------------------------------------
extern "C" void kernel_launch(void* const* d_in, const int* in_sizes, int n_in,
                              void* d_out, int out_size, void* d_ws, size_t ws_size,
                              hipStream_t stream) {
    const float* x     = (const float*)d_in[0];
    const float* qw    = (const float*)d_in[1];
    const float* qb    = (const float*)d_in[2];
    const float* kw    = (const float*)d_in[3];
    const float* kb    = (const float*)d_in[4];
    const float* vw    = (const float*)d_in[5];
    const float* vb    = (const float*)d_in[6];
    const float* gamma = (const float*)d_in[7];
    float* out = (float*)d_out;

    char* ws = (char*)d_ws;
    unsigned short* xT = (unsigned short*)(ws);                  // 33,554,432  [B][N][C] bf16
    unsigned short* wq = (unsigned short*)(ws + 33554432);       //     65,536
    unsigned short* wk = (unsigned short*)(ws + 33619968);       //     65,536
    unsigned short* wv = (unsigned short*)(ws + 33685504);       //    524,288
    unsigned short* Qt = (unsigned short*)(ws + 34209792);       //  4,194,304  [B][N][64] (x log2e)
    unsigned short* Kt = (unsigned short*)(ws + 38404096);       //  4,194,304  [B][N][64]
    unsigned short* Vn = (unsigned short*)(ws + 42598400);       // 33,554,432  [B][512][N]

    wconv_kernel<<<1280, 256, 0, stream>>>(qw, kw, vw, wq, wk, wv);
    xpose_kernel<<<dim3(64, 8, 8), 256, 0, stream>>>(x, xT);
    proj_kernel<1><<<dim3(64, 1, 8), 256, 0, stream>>>(wq, qb, xT, Qt, 1.44269504f);
    proj_kernel<1><<<dim3(64, 1, 8), 256, 0, stream>>>(wk, kb, xT, Kt, 1.0f);
    proj_kernel<0><<<dim3(64, 8, 8), 256, 0, stream>>>(wv, vb, xT, Vn, 1.0f);
    attn_kernel<<<512, 512, 0, stream>>>(Qt, Kt, Vn, gamma, out);
}

// Round 4
// 373.353 us; speedup vs baseline: 1.2939x; 1.2939x over previous
//
#include <hip/hip_runtime.h>
#include <hip/hip_bf16.h>

// Sizes (fixed by problem)
#define BATCH 8
#define CDIM  512
#define NPOS  4096
#define KDQK  64
#define ODIM  512

typedef __attribute__((ext_vector_type(8)))  short short8v;   // 8 bf16 (MFMA A/B frag)
typedef __attribute__((ext_vector_type(16))) float f32x16;    // MFMA 32x32 C/D frag

static __device__ __forceinline__ unsigned short f2bf(float f) {
    union { __hip_bfloat16 h; unsigned short u; } cv;
    cv.h = __float2bfloat16(f);
    return cv.u;
}
static __device__ __forceinline__ float bf2f(unsigned short u) {
    union { unsigned short u; __hip_bfloat16 h; } cv;
    cv.u = u;
    return __bfloat162float(cv.h);
}

// async global->LDS 16B (wave-uniform LDS base + lane*16, per-lane global src)
static __device__ __forceinline__ void gload_lds16(const unsigned short* g, unsigned short* s) {
    __builtin_amdgcn_global_load_lds((const __attribute__((address_space(1))) unsigned int*)g,
                                     (__attribute__((address_space(3))) unsigned int*)s, 16, 0, 0);
}

static __device__ __forceinline__ int cvtpk(float a, float b) {
    int r;
    asm("v_cvt_pk_bf16_f32 %0, %1, %2" : "=v"(r) : "v"(a), "v"(b));
    return r;
}

#if __has_builtin(__builtin_amdgcn_exp2f)
static __device__ __forceinline__ float exp2_raw(float x) { return __builtin_amdgcn_exp2f(x); }
#else
static __device__ __forceinline__ float exp2_raw(float x) { return exp2f(x); }
#endif

// ---------------------------------------------------------------------------
// Kernel 1: convert q_w/k_w/v_w fp32 -> bf16 into workspace
// ---------------------------------------------------------------------------
__global__ __launch_bounds__(256) void wconv_kernel(const float* __restrict__ qw,
                                                    const float* __restrict__ kw,
                                                    const float* __restrict__ vw,
                                                    unsigned short* __restrict__ wq,
                                                    unsigned short* __restrict__ wk,
                                                    unsigned short* __restrict__ wv) {
    int idx = blockIdx.x * 256 + threadIdx.x;
    if (idx < 32768)        wq[idx]          = f2bf(qw[idx]);
    else if (idx < 65536)   wk[idx - 32768]  = f2bf(kw[idx - 32768]);
    else if (idx < 327680)  wv[idx - 65536]  = f2bf(vw[idx - 65536]);
}

// ---------------------------------------------------------------------------
// Kernel 2: x [B][C][N] fp32 -> xT [B][N][C] bf16   (64x64 tiles via LDS)
// ---------------------------------------------------------------------------
__global__ __launch_bounds__(256) void xpose_kernel(const float* __restrict__ x,
                                                    unsigned short* __restrict__ xT) {
    __shared__ float xs[64][65];
    const int b = blockIdx.z, c0 = blockIdx.y * 64, n0 = blockIdx.x * 64;
    const int t = threadIdx.x;
    #pragma unroll
    for (int it = 0; it < 4; ++it) {
        int lin = it * 256 + t;
        int c = lin >> 4, nq = lin & 15;
        const float4 v = *reinterpret_cast<const float4*>(
            x + ((size_t)(b * CDIM + c0 + c) * NPOS + n0 + nq * 4));
        xs[c][nq * 4 + 0] = v.x; xs[c][nq * 4 + 1] = v.y;
        xs[c][nq * 4 + 2] = v.z; xs[c][nq * 4 + 3] = v.w;
    }
    __syncthreads();
    #pragma unroll
    for (int it = 0; it < 4; ++it) {
        int lin = it * 256 + t;
        int n = lin >> 4, cq = lin & 15;
        ushort4 u;
        u.x = f2bf(xs[cq * 4 + 0][n]); u.y = f2bf(xs[cq * 4 + 1][n]);
        u.z = f2bf(xs[cq * 4 + 2][n]); u.w = f2bf(xs[cq * 4 + 3][n]);
        *reinterpret_cast<ushort4*>(xT + ((size_t)(b * NPOS + n0 + n) * CDIM + c0 + cq * 4)) = u;
    }
}

// ---------------------------------------------------------------------------
// Kernel 3: projection GEMM  Y = (W * x + bias) * scale
//   TRANS=1: Y[b][n][r]  (position-major, for Q/K, R=64)
//   TRANS=0: Y[b][r][n]  (natural, for V, R=512)
// ---------------------------------------------------------------------------
template <int TRANS>
__global__ __launch_bounds__(256) void proj_kernel(const unsigned short* __restrict__ W,
                                                   const float* __restrict__ bias,
                                                   const unsigned short* __restrict__ xT,
                                                   unsigned short* __restrict__ Y,
                                                   float scale) {
    __shared__ unsigned short Wl[64][64];
    __shared__ unsigned short Xl[64][64];
    const int b = blockIdx.z, r0 = blockIdx.y * 64, n0 = blockIdx.x * 64;
    const int t = threadIdx.x, wave = t >> 6, lane = t & 63, hi = lane >> 5, lo = lane & 31;
    const int wr = wave >> 1, wc = wave & 1;

    f32x16 acc;
    #pragma unroll
    for (int q = 0; q < 16; ++q) acc[q] = 0.f;

    for (int ck = 0; ck < CDIM; ck += 64) {
        __syncthreads();
        #pragma unroll
        for (int it = 0; it < 2; ++it) {
            int lin = it * 256 + t;
            int r = lin >> 3, c8 = lin & 7;
            int4 v = *reinterpret_cast<const int4*>(W + ((size_t)(r0 + r) * CDIM + ck + c8 * 8));
            *reinterpret_cast<int4*>(&Wl[r][(c8 ^ (r & 7)) * 8]) = v;
        }
        #pragma unroll
        for (int it = 0; it < 2; ++it) {
            int lin = it * 256 + t;
            int n = lin >> 3, c8 = lin & 7;
            int4 v = *reinterpret_cast<const int4*>(
                xT + ((size_t)(b * NPOS + n0 + n) * CDIM + ck + c8 * 8));
            *reinterpret_cast<int4*>(&Xl[n][(c8 ^ (n & 7)) * 8]) = v;
        }
        __syncthreads();
        const int ar = wr * 32 + lo, bn = wc * 32 + lo;
        #pragma unroll
        for (int ks = 0; ks < 4; ++ks) {
            int chunk = 2 * ks + hi;
            short8v a  = *reinterpret_cast<const short8v*>(&Wl[ar][(chunk ^ (ar & 7)) * 8]);
            short8v bb = *reinterpret_cast<const short8v*>(&Xl[bn][(chunk ^ (bn & 7)) * 8]);
            acc = __builtin_amdgcn_mfma_f32_32x32x16_bf16(a, bb, acc, 0, 0, 0);
        }
    }

    const int n = n0 + wc * 32 + lo;
    if (TRANS) {
        #pragma unroll
        for (int g = 0; g < 4; ++g) {
            int rbase = wr * 32 + g * 8 + hi * 4;
            ushort4 u;
            u.x = f2bf((acc[4 * g + 0] + bias[r0 + rbase + 0]) * scale);
            u.y = f2bf((acc[4 * g + 1] + bias[r0 + rbase + 1]) * scale);
            u.z = f2bf((acc[4 * g + 2] + bias[r0 + rbase + 2]) * scale);
            u.w = f2bf((acc[4 * g + 3] + bias[r0 + rbase + 3]) * scale);
            *reinterpret_cast<ushort4*>(Y + ((size_t)(b * NPOS + n) * KDQK + r0 + rbase)) = u;
        }
    } else {
        #pragma unroll
        for (int q = 0; q < 16; ++q) {
            int r = r0 + wr * 32 + (q & 3) + 8 * (q >> 2) + 4 * hi;
            Y[(size_t)(b * ODIM + r) * NPOS + n] = f2bf((acc[q] + bias[r]) * scale);
        }
    }
}

// ---------------------------------------------------------------------------
// Kernel 4: flash attention + gamma*out + v
//
// Block: 512 thr / 8 waves; covers QB=256 queries x OD=256 (od-half); JB=64.
// Grid = 16 qt x 2 odh x 8 b = 256 blocks = 1/CU; bid&7=b pins V[b] to XCD b.
// Wave w owns i-slice [32w,32w+32): QK^T + softmax fully in-wave (m,l per-lane
// persistent, no duplication). Cross-wave data: P[256][64] (bf16, swizzled)
// and cb[256] (rescale factors). PV: wave w owns od rows [32w,32w+32), V from
// LDS (coalesced gload_lds staging, dbuf), P B-frags from LDS.
// All LDS rows 128B + 16B-chunk XOR swizzle -> bank-floor reads.
// 2 barriers/tile; K/V stages for t+1 issued at top of PV(t), drained by the
// implicit vmcnt(0) of the following __syncthreads (full PV phase as cover).
// ---------------------------------------------------------------------------
__global__ __launch_bounds__(512, 2) void attn_kernel(const unsigned short* __restrict__ Qt,
                                                      const unsigned short* __restrict__ Kt,
                                                      const unsigned short* __restrict__ V,
                                                      const float* __restrict__ gamma_p,
                                                      float* __restrict__ out) {
    __shared__ __align__(16) unsigned short Kbuf[2][64 * 64];    // [j][kd] rows 128B, ^(j&7)
    __shared__ __align__(16) unsigned short Vbuf[2][256 * 64];   // [od][j] rows 128B, ^(od&7)
    __shared__ __align__(16) unsigned short Pl[256 * 64];        // [i][j]  rows 128B, ^(i&7)
    __shared__ float cb[256];
    __shared__ float lb[256];

    const int bid = blockIdx.x;
    const int b = bid & 7, r = bid >> 3, odh = r & 1, qt = r >> 1;
    const int i0 = qt * 256, od0 = odh * 256;
    const int tid = threadIdx.x, w = tid >> 6, l = tid & 63, lo = l & 31, hi = l >> 5;
    const int key = lo & 7;

    // ---- staging sources (pre-swizzled: linear gload_lds dest == swizzled layout)
    const int krow = w * 8 + (l >> 3);
    const unsigned short* kp = Kt + ((size_t)b * NPOS + krow) * 64 + (((l & 7) ^ (krow & 7)) << 3);
    const unsigned short* vp[4];
    int vrow_[4];
    #pragma unroll
    for (int v = 0; v < 4; ++v) {
        int vrow = w * 32 + v * 8 + (l >> 3);
        vrow_[v] = vrow;
        vp[v] = V + ((size_t)(b * ODIM + od0 + vrow)) * NPOS + (((l & 7) ^ (vrow & 7)) << 3);
    }

    // ---- Q fragments (B-operand: lane = query col i = 32w+lo, 8 kd per chunk)
    short8v qf[4];
    {
        const unsigned short* qb = Qt + ((size_t)b * NPOS + i0 + w * 32 + lo) * 64 + hi * 8;
        #pragma unroll
        for (int kc = 0; kc < 4; ++kc)
            qf[kc] = *reinterpret_cast<const short8v*>(qb + kc * 16);
    }

    f32x16 acc[8];
    #pragma unroll
    for (int it = 0; it < 8; ++it)
        #pragma unroll
        for (int q = 0; q < 16; ++q) acc[it][q] = 0.f;

    float m_run = -1e30f, l_run = 0.f;

    // prologue: stage tile 0 into buf 0
    gload_lds16(kp, &Kbuf[0][w * 512]);
    #pragma unroll
    for (int v = 0; v < 4; ++v) gload_lds16(vp[v], &Vbuf[0][(w * 32 + v * 8) * 64]);
    __syncthreads();

    for (int t = 0; t < NPOS / 64; ++t) {
        const int cur = t & 1;

        // ---------------- Phase A: QK^T + in-wave softmax + P/cb write --------
        f32x16 s0, s1;
        #pragma unroll
        for (int q = 0; q < 16; ++q) { s0[q] = 0.f; s1[q] = 0.f; }
        const unsigned short* KB = &Kbuf[cur][0];
        #pragma unroll
        for (int kc = 0; kc < 4; ++kc) {
            int cpos = ((2 * kc + hi) ^ key) << 3;
            short8v a0 = *reinterpret_cast<const short8v*>(KB + lo * 64 + cpos);
            short8v a1 = *reinterpret_cast<const short8v*>(KB + (32 + lo) * 64 + cpos);
            s0 = __builtin_amdgcn_mfma_f32_32x32x16_bf16(a0, qf[kc], s0, 0, 0, 0);
            s1 = __builtin_amdgcn_mfma_f32_32x32x16_bf16(a1, qf[kc], s1, 0, 0, 0);
        }
        // tile max over the 32 j this lane holds + pair lane (hi^1)
        float mx = fmaxf(s0[0], s1[0]);
        #pragma unroll
        for (int q = 1; q < 16; ++q) mx = fmaxf(mx, fmaxf(s0[q], s1[q]));
        mx = fmaxf(mx, __shfl_xor(mx, 32));

        bool g = mx > m_run + 12.f;                 // defer-max (log2 domain)
        float c = g ? exp2_raw(m_run - mx) : 1.f;
        if (g) m_run = mx;

        float rs = 0.f;
        #pragma unroll
        for (int q = 0; q < 16; ++q) {
            s0[q] = exp2_raw(s0[q] - m_run); rs += s0[q];
            s1[q] = exp2_raw(s1[q] - m_run); rs += s1[q];
        }
        rs += __shfl_xor(rs, 32);
        l_run = l_run * c + rs;
        if (hi == 0) cb[w * 32 + lo] = c;

        {   // P write: row i = 32w+lo, j = 32jh+8m+4hi+d, chunk = (4jh+m)^key
            unsigned short* prow = &Pl[(w * 32 + lo) * 64];
            #pragma unroll
            for (int m = 0; m < 4; ++m) {
                int w0 = cvtpk(s0[4 * m + 0], s0[4 * m + 1]);
                int w1 = cvtpk(s0[4 * m + 2], s0[4 * m + 3]);
                *reinterpret_cast<int2*>(prow + ((m ^ key) << 3) + hi * 4) = make_int2(w0, w1);
                int w2 = cvtpk(s1[4 * m + 0], s1[4 * m + 1]);
                int w3 = cvtpk(s1[4 * m + 2], s1[4 * m + 3]);
                *reinterpret_cast<int2*>(prow + (((4 + m) ^ key) << 3) + hi * 4) = make_int2(w2, w3);
            }
        }
        __syncthreads();   // B1: P/cb visible; all waves past phase C(t-1)

        // ---------------- Phase C: stage t+1, rescale, PV ----------------
        if (t + 1 < NPOS / 64) {
            const int nb = cur ^ 1;
            gload_lds16(kp + (size_t)(t + 1) * 64 * 64, &Kbuf[nb][w * 512]);
            #pragma unroll
            for (int v = 0; v < 4; ++v)
                gload_lds16(vp[v] + (t + 1) * 64, &Vbuf[nb][(w * 32 + v * 8) * 64]);
        }

        float cv[8];
        #pragma unroll
        for (int it = 0; it < 8; ++it) cv[it] = cb[it * 32 + lo];
        bool need = false;
        #pragma unroll
        for (int it = 0; it < 8; ++it) need = need || (cv[it] != 1.f);
        if (__any(need)) {
            #pragma unroll
            for (int it = 0; it < 8; ++it)
                #pragma unroll
                for (int q = 0; q < 16; ++q) acc[it][q] *= cv[it];
        }

        // V A-frags (od row = 32w+lo local), reused across all 8 it-groups
        const unsigned short* VB = &Vbuf[cur][0];
        short8v va[4];
        #pragma unroll
        for (int kc = 0; kc < 4; ++kc)
            va[kc] = *reinterpret_cast<const short8v*>(
                VB + (w * 32 + lo) * 64 + (((2 * kc + hi) ^ key) << 3));

        #pragma unroll
        for (int it = 0; it < 8; ++it) {
            const unsigned short* prow = &Pl[(it * 32 + lo) * 64];
            #pragma unroll
            for (int kc = 0; kc < 4; ++kc) {
                short8v pb = *reinterpret_cast<const short8v*>(
                    prow + (((2 * kc + hi) ^ key) << 3));
                acc[it] = __builtin_amdgcn_mfma_f32_32x32x16_bf16(va[kc], pb, acc[it], 0, 0, 0);
            }
        }
        __syncthreads();   // B2: drains stages (vmcnt 0), guards P WAR
    }

    // ---------------- epilogue: out = gamma*O/l + v ----------------
    if (hi == 0) lb[w * 32 + lo] = l_run;
    __syncthreads();
    float linv[8];
    #pragma unroll
    for (int it = 0; it < 8; ++it) linv[it] = 1.0f / lb[it * 32 + lo];
    const float gm = gamma_p[0];
    #pragma unroll
    for (int it = 0; it < 8; ++it) {
        #pragma unroll
        for (int q = 0; q < 16; ++q) {
            int od = od0 + w * 32 + (q & 3) + 8 * (q >> 2) + 4 * hi;
            int i = i0 + it * 32 + lo;
            size_t addr = ((size_t)b * ODIM + od) * NPOS + i;
            out[addr] = gm * acc[it][q] * linv[it] + bf2f(V[addr]);
        }
    }
}

// ---------------------------------------------------------------------------
// Host launcher
// ---------------------------------------------------------------------------
extern "C" void kernel_launch(void* const* d_in, const int* in_sizes, int n_in,
                              void* d_out, int out_size, void* d_ws, size_t ws_size,
                              hipStream_t stream) {
    const float* x     = (const float*)d_in[0];
    const float* qw    = (const float*)d_in[1];
    const float* qb    = (const float*)d_in[2];
    const float* kw    = (const float*)d_in[3];
    const float* kb    = (const float*)d_in[4];
    const float* vw    = (const float*)d_in[5];
    const float* vb    = (const float*)d_in[6];
    const float* gamma = (const float*)d_in[7];
    float* out = (float*)d_out;

    char* ws = (char*)d_ws;
    unsigned short* xT = (unsigned short*)(ws);                  // 33,554,432  [B][N][C] bf16
    unsigned short* wq = (unsigned short*)(ws + 33554432);       //     65,536
    unsigned short* wk = (unsigned short*)(ws + 33619968);       //     65,536
    unsigned short* wv = (unsigned short*)(ws + 33685504);       //    524,288
    unsigned short* Qt = (unsigned short*)(ws + 34209792);       //  4,194,304  [B][N][64] (x log2e)
    unsigned short* Kt = (unsigned short*)(ws + 38404096);       //  4,194,304  [B][N][64]
    unsigned short* Vn = (unsigned short*)(ws + 42598400);       // 33,554,432  [B][512][N]

    wconv_kernel<<<1280, 256, 0, stream>>>(qw, kw, vw, wq, wk, wv);
    xpose_kernel<<<dim3(64, 8, 8), 256, 0, stream>>>(x, xT);
    proj_kernel<1><<<dim3(64, 1, 8), 256, 0, stream>>>(wq, qb, xT, Qt, 1.44269504f);
    proj_kernel<1><<<dim3(64, 1, 8), 256, 0, stream>>>(wk, kb, xT, Kt, 1.0f);
    proj_kernel<0><<<dim3(64, 8, 8), 256, 0, stream>>>(wv, vb, xT, Vn, 1.0f);
    attn_kernel<<<256, 512, 0, stream>>>(Qt, Kt, Vn, gamma, out);
}